// Round 21
// baseline (135.313 us; speedup 1.0000x reference)
//
#include <hip/hip_runtime.h>
#include <stdint.h>

#define N_NODES 50000
#define N_EDGES 400000
#define DDIM 256
#define MASK_WORDS 400000  // 50000*256/32
#define EDGE_CAP 64        // padded CSR row capacity (max in-degree ~30)
#define EDGE_BLOCKS 196    // ceil(400000/8/256), 8 edges per thread
#define MASK_BLOCKS 1563   // ceil(400000/256)
#define FCONV_BLOCKS 6250  // 50000*256/8 / 256

typedef __attribute__((ext_vector_type(8))) short bf16x8;
typedef __attribute__((ext_vector_type(4))) float f32x4;

// ---------------------------------------------------------------------------
// JAX threefry2x32, key = (0, 42).  Partitionable scheme (verified round 5):
// element with flat index j uses counter (0, j); draw = out0 ^ out1.
// ---------------------------------------------------------------------------
__device__ __forceinline__ uint32_t rotl32(uint32_t x, uint32_t r) {
  return (x << r) | (x >> (32u - r));
}

__device__ __forceinline__ uint32_t threefry_draw_0_42(uint32_t x0, uint32_t x1) {
  const uint32_t k0 = 0u, k1 = 42u;
  const uint32_t k2 = k0 ^ k1 ^ 0x1BD11BDAu;
  x0 += k0;
  x1 += k1;
#define TF_ROUND(r)          \
  {                          \
    x0 += x1;                \
    x1 = rotl32(x1, r);      \
    x1 ^= x0;                \
  }
  TF_ROUND(13) TF_ROUND(15) TF_ROUND(26) TF_ROUND(6)
  x0 += k1; x1 += k2 + 1u;
  TF_ROUND(17) TF_ROUND(29) TF_ROUND(16) TF_ROUND(24)
  x0 += k2; x1 += k0 + 2u;
  TF_ROUND(13) TF_ROUND(15) TF_ROUND(26) TF_ROUND(6)
  x0 += k0; x1 += k1 + 3u;
  TF_ROUND(17) TF_ROUND(29) TF_ROUND(16) TF_ROUND(24)
  x0 += k1; x1 += k2 + 4u;
  TF_ROUND(13) TF_ROUND(15) TF_ROUND(26) TF_ROUND(6)
  x0 += k2; x1 += k0 + 5u;
#undef TF_ROUND
  return x0 ^ x1;
}

__device__ __forceinline__ uint16_t bf16_rne(float x) {
  uint32_t u = __float_as_uint(x);
  u += 0x7FFFu + ((u >> 16) & 1u);
  return (uint16_t)(u >> 16);
}

// ---------------------------------------------------------------------------
// 1) setup + mask: blocks 0-97 zero deg_out+deg_in (25000 int4);
//    blocks 98-161 transpose W fp32 [k][n] -> Wt bf16 [n][k];
//    blocks 162-1724 dropout bitmask (pure VALU — runs here uncontended;
//    r18-r20 showed it refuses to hide under busy kernels).
// ---------------------------------------------------------------------------
__global__ __launch_bounds__(256) void setup_mask_kernel(
    const float* __restrict__ W, uint16_t* __restrict__ Wt,
    int4* __restrict__ zero_base, uint32_t* __restrict__ mask) {
  const int bid = blockIdx.x;
  if (bid < 98) {
    const int t = bid * 256 + threadIdx.x;
    if (t < 25000) zero_base[t] = make_int4(0, 0, 0, 0);
  } else if (bid < 162) {
    const int t = (bid - 98) * 256 + threadIdx.x;  // 0..16383
    const int n = t >> 6;
    const int k4 = (t & 63) << 2;
    ushort4 p;
    p.x = bf16_rne(W[(size_t)(k4 + 0) * DDIM + n]);
    p.y = bf16_rne(W[(size_t)(k4 + 1) * DDIM + n]);
    p.z = bf16_rne(W[(size_t)(k4 + 2) * DDIM + n]);
    p.w = bf16_rne(W[(size_t)(k4 + 3) * DDIM + n]);
    *(ushort4*)(Wt + (size_t)n * DDIM + k4) = p;
  } else {
    // dropout bitmask; keep(j) <=> (draw>>9) < 7549747 (== u<0.9f exactly)
    const uint32_t t = (uint32_t)(bid - 162) * 256u + (uint32_t)threadIdx.x;
    if (t < MASK_WORDS) {
      const uint32_t base = t * 32u;
      uint32_t w = 0u;
#pragma unroll
      for (uint32_t b = 0; b < 32u; ++b) {
        const uint32_t bits = threefry_draw_0_42(0u, base + b);
        w |= ((bits >> 9) < 7549747u) ? (1u << b) : 0u;
      }
      mask[t] = w;
    }
  }
}

// ---------------------------------------------------------------------------
// 2) prep (r19-measured 33us config): edge pass + fconv, NO mask.
//      [0, 196)      edge pass, 8 edges/thread (2x int4 loads; 16
//                    independent atomic chains/thread):
//                    deg_out histogram + deg_in cursor + esrc store
//      [196, 6446)   featb = bf16(feat)  (pure convert, BW-bound)
// ---------------------------------------------------------------------------
__global__ __launch_bounds__(256) void mega_prep_kernel(
    const float* __restrict__ feat, const int* __restrict__ src,
    const int* __restrict__ dst, int* __restrict__ deg_out,
    int* __restrict__ deg_in, int* __restrict__ esrc,
    uint16_t* __restrict__ featb) {
  const int bid = blockIdx.x;
  if (bid < EDGE_BLOCKS) {
    const int base = (bid * 256 + threadIdx.x) * 8;
    if (base < N_EDGES) {  // N_EDGES%8==0 -> full int4 pairs in bounds
      const int4 sa = *(const int4*)(src + base);
      const int4 sb = *(const int4*)(src + base + 4);
      const int4 da = *(const int4*)(dst + base);
      const int4 db = *(const int4*)(dst + base + 4);
      atomicAdd(&deg_out[sa.x], 1);
      atomicAdd(&deg_out[sa.y], 1);
      atomicAdd(&deg_out[sa.z], 1);
      atomicAdd(&deg_out[sa.w], 1);
      atomicAdd(&deg_out[sb.x], 1);
      atomicAdd(&deg_out[sb.y], 1);
      atomicAdd(&deg_out[sb.z], 1);
      atomicAdd(&deg_out[sb.w], 1);
      const int p0 = atomicAdd(&deg_in[da.x], 1);
      const int p1 = atomicAdd(&deg_in[da.y], 1);
      const int p2 = atomicAdd(&deg_in[da.z], 1);
      const int p3 = atomicAdd(&deg_in[da.w], 1);
      const int p4 = atomicAdd(&deg_in[db.x], 1);
      const int p5 = atomicAdd(&deg_in[db.y], 1);
      const int p6 = atomicAdd(&deg_in[db.z], 1);
      const int p7 = atomicAdd(&deg_in[db.w], 1);
      if (p0 < EDGE_CAP) esrc[(da.x << 6) + p0] = sa.x;
      if (p1 < EDGE_CAP) esrc[(da.y << 6) + p1] = sa.y;
      if (p2 < EDGE_CAP) esrc[(da.z << 6) + p2] = sa.z;
      if (p3 < EDGE_CAP) esrc[(da.w << 6) + p3] = sa.w;
      if (p4 < EDGE_CAP) esrc[(db.x << 6) + p4] = sb.x;
      if (p5 < EDGE_CAP) esrc[(db.y << 6) + p5] = sb.y;
      if (p6 < EDGE_CAP) esrc[(db.z << 6) + p6] = sb.z;
      if (p7 < EDGE_CAP) esrc[(db.w << 6) + p7] = sb.w;
    }
  } else {
    // featb = bf16(feat)  (unscaled; gather applies rsqrt(deg_out) per edge)
    const int t = (bid - EDGE_BLOCKS) * 256 + threadIdx.x;
    const size_t base = (size_t)t * 8;
    const float4 a = *(const float4*)(feat + base);
    const float4 b = *(const float4*)(feat + base + 4);
    ushort4 lo, hi;
    lo.x = bf16_rne(a.x); lo.y = bf16_rne(a.y);
    lo.z = bf16_rne(a.z); lo.w = bf16_rne(a.w);
    hi.x = bf16_rne(b.x); hi.y = bf16_rne(b.y);
    hi.z = bf16_rne(b.z); hi.w = bf16_rne(b.w);
    *(ushort4*)(featb + base) = lo;
    *(ushort4*)(featb + base + 4) = hi;
  }
}

// ---------------------------------------------------------------------------
// 3) pull-mode aggregate (r17/r18-proven): FULL wave per node; lane owns
//    4 bf16 (uint2, 8B) of the 256-col row.  8 edge rows + deg scales
//    issued back-to-back, fp32 fma accumulate; 4/2/1 ladder tail.
//    scale = rsqrt(max(deg_out[src],1)).
// ---------------------------------------------------------------------------
__device__ __forceinline__ void acc4s(float* a, uint2 q, float sc) {
  a[0] = fmaf(__uint_as_float(q.x << 16), sc, a[0]);
  a[1] = fmaf(__uint_as_float(q.x & 0xFFFF0000u), sc, a[1]);
  a[2] = fmaf(__uint_as_float(q.y << 16), sc, a[2]);
  a[3] = fmaf(__uint_as_float(q.y & 0xFFFF0000u), sc, a[3]);
}

__device__ __forceinline__ float dscale(const int* deg, int s) {
  return rsqrtf(fmaxf((float)deg[s], 1.0f));
}

__global__ __launch_bounds__(256) void gather_kernel(
    const uint16_t* __restrict__ featb, const int* __restrict__ deg_out,
    const int* __restrict__ deg_in, const int* __restrict__ esrc,
    uint16_t* __restrict__ agg) {
  const int n = blockIdx.x * 4 + (threadIdx.x >> 6);
  if (n >= N_NODES) return;
  const int lane = threadIdx.x & 63;
  const size_t coff = (size_t)(lane << 2);  // 4 bf16 = 8 B per lane
  const int beg = n << 6;
  const int cnt = min(deg_in[n], EDGE_CAP);

  float a[4] = {};
  int j = 0;
  for (; j + 8 <= cnt; j += 8) {
    const int4 e0 = *(const int4*)(esrc + beg + j);
    const int4 e1 = *(const int4*)(esrc + beg + j + 4);
    const uint2 q0 = *(const uint2*)(featb + (size_t)e0.x * DDIM + coff);
    const uint2 q1 = *(const uint2*)(featb + (size_t)e0.y * DDIM + coff);
    const uint2 q2 = *(const uint2*)(featb + (size_t)e0.z * DDIM + coff);
    const uint2 q3 = *(const uint2*)(featb + (size_t)e0.w * DDIM + coff);
    const uint2 q4 = *(const uint2*)(featb + (size_t)e1.x * DDIM + coff);
    const uint2 q5 = *(const uint2*)(featb + (size_t)e1.y * DDIM + coff);
    const uint2 q6 = *(const uint2*)(featb + (size_t)e1.z * DDIM + coff);
    const uint2 q7 = *(const uint2*)(featb + (size_t)e1.w * DDIM + coff);
    const float s0 = dscale(deg_out, e0.x);
    const float s1 = dscale(deg_out, e0.y);
    const float s2 = dscale(deg_out, e0.z);
    const float s3 = dscale(deg_out, e0.w);
    const float s4 = dscale(deg_out, e1.x);
    const float s5 = dscale(deg_out, e1.y);
    const float s6 = dscale(deg_out, e1.z);
    const float s7 = dscale(deg_out, e1.w);
    acc4s(a, q0, s0); acc4s(a, q1, s1); acc4s(a, q2, s2); acc4s(a, q3, s3);
    acc4s(a, q4, s4); acc4s(a, q5, s5); acc4s(a, q6, s6); acc4s(a, q7, s7);
  }
  if (j + 4 <= cnt) {
    const int4 e0 = *(const int4*)(esrc + beg + j);
    const uint2 q0 = *(const uint2*)(featb + (size_t)e0.x * DDIM + coff);
    const uint2 q1 = *(const uint2*)(featb + (size_t)e0.y * DDIM + coff);
    const uint2 q2 = *(const uint2*)(featb + (size_t)e0.z * DDIM + coff);
    const uint2 q3 = *(const uint2*)(featb + (size_t)e0.w * DDIM + coff);
    const float s0 = dscale(deg_out, e0.x);
    const float s1 = dscale(deg_out, e0.y);
    const float s2 = dscale(deg_out, e0.z);
    const float s3 = dscale(deg_out, e0.w);
    acc4s(a, q0, s0); acc4s(a, q1, s1); acc4s(a, q2, s2); acc4s(a, q3, s3);
    j += 4;
  }
  if (j + 2 <= cnt) {
    const int s0i = esrc[beg + j];
    const int s1i = esrc[beg + j + 1];
    const uint2 q0 = *(const uint2*)(featb + (size_t)s0i * DDIM + coff);
    const uint2 q1 = *(const uint2*)(featb + (size_t)s1i * DDIM + coff);
    acc4s(a, q0, dscale(deg_out, s0i));
    acc4s(a, q1, dscale(deg_out, s1i));
    j += 2;
  }
  if (j < cnt) {
    const int s0i = esrc[beg + j];
    const uint2 q0 = *(const uint2*)(featb + (size_t)s0i * DDIM + coff);
    acc4s(a, q0, dscale(deg_out, s0i));
  }

  uint2 p;
  p.x = (uint32_t)bf16_rne(a[0]) | ((uint32_t)bf16_rne(a[1]) << 16);
  p.y = (uint32_t)bf16_rne(a[2]) | ((uint32_t)bf16_rne(a[3]) << 16);
  *(uint2*)(agg + (size_t)n * DDIM + coff) = p;
}

// ---------------------------------------------------------------------------
// 4) out = dropout(relu((agg @ W) * rsqrt(max(deg_in,1)) + b))
//    MFMA bf16 16x16x32.  Block = 64 rows x 256 cols, 4 waves (wave: 64x64).
//    A staged once in LDS (37 KB -> 4 blocks/CU); B direct from L2 Wt.
// ---------------------------------------------------------------------------
#define APAD 280  // shorts per As row (560 B, 16B-aligned)
__global__ __launch_bounds__(256, 4) void gemm_mfma_kernel(
    const uint16_t* __restrict__ agg, const uint16_t* __restrict__ Wt,
    const float* __restrict__ bias, const int* __restrict__ deg_in,
    const uint32_t* __restrict__ mask, float* __restrict__ out) {
  __shared__ short As[64 * APAD];
  __shared__ float sdeg[64];
  __shared__ float sbias[256];

  const int tid = threadIdx.x;
  const int r0 = blockIdx.x * 64;
  const int lane = tid & 63;
  const int seg = lane >> 4;  // k-segment 0..3
  const int l15 = lane & 15;
  const int wc = tid >> 6;  // wave -> col panel (64 cols each)

  sbias[tid] = bias[tid];
  if (tid < 64) {
    const int r = r0 + tid;
    sdeg[tid] = (r < N_NODES) ? rsqrtf(fmaxf((float)deg_in[r], 1.0f)) : 0.0f;
  }

  // stage A panel: 64 rows x 256 k bf16 (2048 x 16B chunks, coalesced)
  {
    const uint16_t* ap = agg + (size_t)r0 * DDIM;
#pragma unroll
    for (int it = 0; it < 8; ++it) {
      const int c = tid + 256 * it;
      const int row = c >> 5;        // 32 chunks per row
      const int k8 = (c & 31) << 3;  // 0,8,...,248
      int4 v = make_int4(0, 0, 0, 0);
      if (r0 + row < N_NODES) v = *(const int4*)(ap + (size_t)row * DDIM + k8);
      *(int4*)&As[row * APAD + k8] = v;
    }
  }
  __syncthreads();

  const uint16_t* wt_base = Wt + (size_t)(wc * 64 + l15) * DDIM + seg * 8;

  f32x4 acc[4][4] = {};
#pragma unroll
  for (int kkI = 0; kkI < 8; ++kkI) {
    const int kk = kkI * 32;
    bf16x8 a[4], b[4];
#pragma unroll
    for (int m = 0; m < 4; ++m)
      a[m] = *(const bf16x8*)&As[(m * 16 + l15) * APAD + kk + seg * 8];
#pragma unroll
    for (int n = 0; n < 4; ++n)
      b[n] = *(const bf16x8*)(wt_base + n * 16 * DDIM + kk);
#pragma unroll
    for (int m = 0; m < 4; ++m)
#pragma unroll
      for (int n = 0; n < 4; ++n)
        acc[m][n] = __builtin_amdgcn_mfma_f32_16x16x32_bf16(a[m], b[n], acc[m][n], 0, 0, 0);
  }

  // epilogue: C/D layout col = lane&15, row = seg*4 + reg
  constexpr float INV09 = 1.0f / 0.9f;
#pragma unroll
  for (int m = 0; m < 4; ++m) {
#pragma unroll
    for (int r = 0; r < 4; ++r) {
      const int lrow = m * 16 + seg * 4 + r;
      const int row = r0 + lrow;
      if (row >= N_NODES) continue;
      const float s = sdeg[lrow];
      const uint32_t w0 = mask[row * 8 + wc * 2];      // cols wc*64 .. +31
      const uint32_t w1 = mask[row * 8 + wc * 2 + 1];  // cols wc*64+32 .. +63
#pragma unroll
      for (int n = 0; n < 4; ++n) {
        const int col = wc * 64 + n * 16 + l15;
        float v = fmaxf(acc[m][n][r] * s + sbias[col], 0.0f);
        const uint32_t w = (n < 2) ? w0 : w1;
        const uint32_t bit = (uint32_t)((n & 1) * 16 + l15);
        out[(size_t)row * DDIM + col] = ((w >> bit) & 1u) ? v * INV09 : 0.0f;
      }
    }
  }
}

// ---------------------------------------------------------------------------
// ws layout (bytes; ws_size ~268 MB per harness poison fill):
//   deg_out   @ 0          (200000)
//   deg_in    @ 200000     (200000)
//   esrc      @ 400000     (12800000)  padded CSR [n][64]
//   Wt bf16   @ 13200000   (131072)
//   featb bf16@ 13331072   (25600000)
//   mask u32  @ 38931072   (1600000)
//   agg bf16  @ 40531072   (25600000)  total ~66 MB
// ---------------------------------------------------------------------------
extern "C" void kernel_launch(void* const* d_in, const int* in_sizes, int n_in,
                              void* d_out, int out_size, void* d_ws, size_t ws_size,
                              hipStream_t stream) {
  const float* feat = (const float*)d_in[0];
  const float* W = (const float*)d_in[1];
  const float* bias = (const float*)d_in[2];
  const int* src = (const int*)d_in[3];
  const int* dst = (const int*)d_in[4];
  float* out = (float*)d_out;

  char* ws = (char*)d_ws;
  int* deg_out = (int*)(ws + 0);
  int* deg_in = (int*)(ws + 200000);
  int* esrc = (int*)(ws + 400000);
  uint16_t* Wt = (uint16_t*)(ws + 13200000);
  uint16_t* featb = (uint16_t*)(ws + 13331072);
  uint32_t* mask = (uint32_t*)(ws + 38931072);
  uint16_t* agg = (uint16_t*)(ws + 40531072);

  setup_mask_kernel<<<162 + MASK_BLOCKS, 256, 0, stream>>>(W, Wt, (int4*)d_ws, mask);
  mega_prep_kernel<<<EDGE_BLOCKS + FCONV_BLOCKS, 256, 0, stream>>>(
      feat, src, dst, deg_out, deg_in, esrc, featb);
  gather_kernel<<<(N_NODES + 3) / 4, 256, 0, stream>>>(featb, deg_out, deg_in, esrc, agg);
  gemm_mfma_kernel<<<(N_NODES + 63) / 64, 256, 0, stream>>>(agg, Wt, bias, deg_in, mask, out);
}

// Round 22
// 112.169 us; speedup vs baseline: 1.2063x; 1.2063x over previous
//
#include <hip/hip_runtime.h>
#include <stdint.h>

#define N_NODES 50000
#define N_EDGES 400000
#define DDIM 256
#define MASK_WORDS 400000  // 50000*256/32
#define EDGE_CAP 64        // padded CSR row capacity (max in-degree ~30)
#define EDGE_BLOCKS 98     // ceil(400000/16/256), 16 edges per thread
#define MASK_BLOCKS 1563   // ceil(400000/256)
#define FCONV_BLOCKS 6250  // 50000*256/8 / 256

typedef __attribute__((ext_vector_type(8))) short bf16x8;
typedef __attribute__((ext_vector_type(4))) float f32x4;

// ---------------------------------------------------------------------------
// JAX threefry2x32, key = (0, 42).  Partitionable scheme (verified round 5):
// element with flat index j uses counter (0, j); draw = out0 ^ out1.
// ---------------------------------------------------------------------------
__device__ __forceinline__ uint32_t rotl32(uint32_t x, uint32_t r) {
  return (x << r) | (x >> (32u - r));
}

__device__ __forceinline__ uint32_t threefry_draw_0_42(uint32_t x0, uint32_t x1) {
  const uint32_t k0 = 0u, k1 = 42u;
  const uint32_t k2 = k0 ^ k1 ^ 0x1BD11BDAu;
  x0 += k0;
  x1 += k1;
#define TF_ROUND(r)          \
  {                          \
    x0 += x1;                \
    x1 = rotl32(x1, r);      \
    x1 ^= x0;                \
  }
  TF_ROUND(13) TF_ROUND(15) TF_ROUND(26) TF_ROUND(6)
  x0 += k1; x1 += k2 + 1u;
  TF_ROUND(17) TF_ROUND(29) TF_ROUND(16) TF_ROUND(24)
  x0 += k2; x1 += k0 + 2u;
  TF_ROUND(13) TF_ROUND(15) TF_ROUND(26) TF_ROUND(6)
  x0 += k0; x1 += k1 + 3u;
  TF_ROUND(17) TF_ROUND(29) TF_ROUND(16) TF_ROUND(24)
  x0 += k1; x1 += k2 + 4u;
  TF_ROUND(13) TF_ROUND(15) TF_ROUND(26) TF_ROUND(6)
  x0 += k2; x1 += k0 + 5u;
#undef TF_ROUND
  return x0 ^ x1;
}

__device__ __forceinline__ uint16_t bf16_rne(float x) {
  uint32_t u = __float_as_uint(x);
  u += 0x7FFFu + ((u >> 16) & 1u);
  return (uint16_t)(u >> 16);
}

// ---------------------------------------------------------------------------
// 1) setup: blocks 0-97 zero deg_out+deg_in (25000 int4);
//           blocks 98-161 transpose W fp32 [k][n] -> Wt bf16 [n][k]
// ---------------------------------------------------------------------------
__global__ __launch_bounds__(256) void setup_kernel(
    const float* __restrict__ W, uint16_t* __restrict__ Wt,
    int4* __restrict__ zero_base) {
  const int bid = blockIdx.x;
  if (bid < 98) {
    const int t = bid * 256 + threadIdx.x;
    if (t < 25000) zero_base[t] = make_int4(0, 0, 0, 0);
  } else {
    const int t = (bid - 98) * 256 + threadIdx.x;  // 0..16383
    const int n = t >> 6;
    const int k4 = (t & 63) << 2;
    ushort4 p;
    p.x = bf16_rne(W[(size_t)(k4 + 0) * DDIM + n]);
    p.y = bf16_rne(W[(size_t)(k4 + 1) * DDIM + n]);
    p.z = bf16_rne(W[(size_t)(k4 + 2) * DDIM + n]);
    p.w = bf16_rne(W[(size_t)(k4 + 3) * DDIM + n]);
    *(ushort4*)(Wt + (size_t)n * DDIM + k4) = p;
  }
}

// ---------------------------------------------------------------------------
// 2) MEGA-FUSED prep (r18 structure; edge section now 16 edges/thread):
//      [0, 98)               edge pass, 16 edges/thread (4x int4 loads; 32
//                            independent atomic chains/thread):
//                            deg_out histogram + deg_in cursor + esrc store
//      [98, 1661)            dropout bitmask (pure VALU, hides under edges)
//      [1661, 7911)          featb = bf16(feat)  (pure convert, BW-bound)
//    Disjoint outputs; no section reads another's output.
// ---------------------------------------------------------------------------
__global__ __launch_bounds__(256) void mega_prep_kernel(
    const float* __restrict__ feat, const int* __restrict__ src,
    const int* __restrict__ dst, int* __restrict__ deg_out,
    int* __restrict__ deg_in, int* __restrict__ esrc,
    uint32_t* __restrict__ mask, uint16_t* __restrict__ featb) {
  const int bid = blockIdx.x;
  if (bid < EDGE_BLOCKS) {
    const int base = (bid * 256 + threadIdx.x) * 16;
    if (base < N_EDGES) {  // N_EDGES%16==0 -> full int4 quads in bounds
#pragma unroll
      for (int h = 0; h < 2; ++h) {
        const int b8 = base + h * 8;
        const int4 sa = *(const int4*)(src + b8);
        const int4 sb = *(const int4*)(src + b8 + 4);
        const int4 da = *(const int4*)(dst + b8);
        const int4 db = *(const int4*)(dst + b8 + 4);
        atomicAdd(&deg_out[sa.x], 1);
        atomicAdd(&deg_out[sa.y], 1);
        atomicAdd(&deg_out[sa.z], 1);
        atomicAdd(&deg_out[sa.w], 1);
        atomicAdd(&deg_out[sb.x], 1);
        atomicAdd(&deg_out[sb.y], 1);
        atomicAdd(&deg_out[sb.z], 1);
        atomicAdd(&deg_out[sb.w], 1);
        const int p0 = atomicAdd(&deg_in[da.x], 1);
        const int p1 = atomicAdd(&deg_in[da.y], 1);
        const int p2 = atomicAdd(&deg_in[da.z], 1);
        const int p3 = atomicAdd(&deg_in[da.w], 1);
        const int p4 = atomicAdd(&deg_in[db.x], 1);
        const int p5 = atomicAdd(&deg_in[db.y], 1);
        const int p6 = atomicAdd(&deg_in[db.z], 1);
        const int p7 = atomicAdd(&deg_in[db.w], 1);
        if (p0 < EDGE_CAP) esrc[(da.x << 6) + p0] = sa.x;
        if (p1 < EDGE_CAP) esrc[(da.y << 6) + p1] = sa.y;
        if (p2 < EDGE_CAP) esrc[(da.z << 6) + p2] = sa.z;
        if (p3 < EDGE_CAP) esrc[(da.w << 6) + p3] = sa.w;
        if (p4 < EDGE_CAP) esrc[(db.x << 6) + p4] = sb.x;
        if (p5 < EDGE_CAP) esrc[(db.y << 6) + p5] = sb.y;
        if (p6 < EDGE_CAP) esrc[(db.z << 6) + p6] = sb.z;
        if (p7 < EDGE_CAP) esrc[(db.w << 6) + p7] = sb.w;
      }
    }
  } else if (bid < EDGE_BLOCKS + MASK_BLOCKS) {
    // dropout bitmask; keep(j) <=> (draw>>9) < 7549747 (== u<0.9f exactly)
    const uint32_t t =
        (uint32_t)(bid - EDGE_BLOCKS) * 256u + (uint32_t)threadIdx.x;
    if (t < MASK_WORDS) {
      const uint32_t base = t * 32u;
      uint32_t w = 0u;
#pragma unroll
      for (uint32_t b = 0; b < 32u; ++b) {
        const uint32_t bits = threefry_draw_0_42(0u, base + b);
        w |= ((bits >> 9) < 7549747u) ? (1u << b) : 0u;
      }
      mask[t] = w;
    }
  } else {
    // featb = bf16(feat)  (unscaled; gather applies rsqrt(deg_out) per edge)
    const int t = (bid - EDGE_BLOCKS - MASK_BLOCKS) * 256 + threadIdx.x;
    const size_t base = (size_t)t * 8;
    const float4 a = *(const float4*)(feat + base);
    const float4 b = *(const float4*)(feat + base + 4);
    ushort4 lo, hi;
    lo.x = bf16_rne(a.x); lo.y = bf16_rne(a.y);
    lo.z = bf16_rne(a.z); lo.w = bf16_rne(a.w);
    hi.x = bf16_rne(b.x); hi.y = bf16_rne(b.y);
    hi.z = bf16_rne(b.z); hi.w = bf16_rne(b.w);
    *(ushort4*)(featb + base) = lo;
    *(ushort4*)(featb + base + 4) = hi;
  }
}

// ---------------------------------------------------------------------------
// 3) pull-mode aggregate (r17/r18-proven): FULL wave per node; lane owns
//    4 bf16 (uint2, 8B) of the 256-col row.  8 edge rows + deg scales
//    issued back-to-back, fp32 fma accumulate; 4/2/1 ladder tail.
//    scale = rsqrt(max(deg_out[src],1)).
// ---------------------------------------------------------------------------
__device__ __forceinline__ void acc4s(float* a, uint2 q, float sc) {
  a[0] = fmaf(__uint_as_float(q.x << 16), sc, a[0]);
  a[1] = fmaf(__uint_as_float(q.x & 0xFFFF0000u), sc, a[1]);
  a[2] = fmaf(__uint_as_float(q.y << 16), sc, a[2]);
  a[3] = fmaf(__uint_as_float(q.y & 0xFFFF0000u), sc, a[3]);
}

__device__ __forceinline__ float dscale(const int* deg, int s) {
  return rsqrtf(fmaxf((float)deg[s], 1.0f));
}

__global__ __launch_bounds__(256) void gather_kernel(
    const uint16_t* __restrict__ featb, const int* __restrict__ deg_out,
    const int* __restrict__ deg_in, const int* __restrict__ esrc,
    uint16_t* __restrict__ agg) {
  const int n = blockIdx.x * 4 + (threadIdx.x >> 6);
  if (n >= N_NODES) return;
  const int lane = threadIdx.x & 63;
  const size_t coff = (size_t)(lane << 2);  // 4 bf16 = 8 B per lane
  const int beg = n << 6;
  const int cnt = min(deg_in[n], EDGE_CAP);

  float a[4] = {};
  int j = 0;
  for (; j + 8 <= cnt; j += 8) {
    const int4 e0 = *(const int4*)(esrc + beg + j);
    const int4 e1 = *(const int4*)(esrc + beg + j + 4);
    const uint2 q0 = *(const uint2*)(featb + (size_t)e0.x * DDIM + coff);
    const uint2 q1 = *(const uint2*)(featb + (size_t)e0.y * DDIM + coff);
    const uint2 q2 = *(const uint2*)(featb + (size_t)e0.z * DDIM + coff);
    const uint2 q3 = *(const uint2*)(featb + (size_t)e0.w * DDIM + coff);
    const uint2 q4 = *(const uint2*)(featb + (size_t)e1.x * DDIM + coff);
    const uint2 q5 = *(const uint2*)(featb + (size_t)e1.y * DDIM + coff);
    const uint2 q6 = *(const uint2*)(featb + (size_t)e1.z * DDIM + coff);
    const uint2 q7 = *(const uint2*)(featb + (size_t)e1.w * DDIM + coff);
    const float s0 = dscale(deg_out, e0.x);
    const float s1 = dscale(deg_out, e0.y);
    const float s2 = dscale(deg_out, e0.z);
    const float s3 = dscale(deg_out, e0.w);
    const float s4 = dscale(deg_out, e1.x);
    const float s5 = dscale(deg_out, e1.y);
    const float s6 = dscale(deg_out, e1.z);
    const float s7 = dscale(deg_out, e1.w);
    acc4s(a, q0, s0); acc4s(a, q1, s1); acc4s(a, q2, s2); acc4s(a, q3, s3);
    acc4s(a, q4, s4); acc4s(a, q5, s5); acc4s(a, q6, s6); acc4s(a, q7, s7);
  }
  if (j + 4 <= cnt) {
    const int4 e0 = *(const int4*)(esrc + beg + j);
    const uint2 q0 = *(const uint2*)(featb + (size_t)e0.x * DDIM + coff);
    const uint2 q1 = *(const uint2*)(featb + (size_t)e0.y * DDIM + coff);
    const uint2 q2 = *(const uint2*)(featb + (size_t)e0.z * DDIM + coff);
    const uint2 q3 = *(const uint2*)(featb + (size_t)e0.w * DDIM + coff);
    const float s0 = dscale(deg_out, e0.x);
    const float s1 = dscale(deg_out, e0.y);
    const float s2 = dscale(deg_out, e0.z);
    const float s3 = dscale(deg_out, e0.w);
    acc4s(a, q0, s0); acc4s(a, q1, s1); acc4s(a, q2, s2); acc4s(a, q3, s3);
    j += 4;
  }
  if (j + 2 <= cnt) {
    const int s0i = esrc[beg + j];
    const int s1i = esrc[beg + j + 1];
    const uint2 q0 = *(const uint2*)(featb + (size_t)s0i * DDIM + coff);
    const uint2 q1 = *(const uint2*)(featb + (size_t)s1i * DDIM + coff);
    acc4s(a, q0, dscale(deg_out, s0i));
    acc4s(a, q1, dscale(deg_out, s1i));
    j += 2;
  }
  if (j < cnt) {
    const int s0i = esrc[beg + j];
    const uint2 q0 = *(const uint2*)(featb + (size_t)s0i * DDIM + coff);
    acc4s(a, q0, dscale(deg_out, s0i));
  }

  uint2 p;
  p.x = (uint32_t)bf16_rne(a[0]) | ((uint32_t)bf16_rne(a[1]) << 16);
  p.y = (uint32_t)bf16_rne(a[2]) | ((uint32_t)bf16_rne(a[3]) << 16);
  *(uint2*)(agg + (size_t)n * DDIM + coff) = p;
}

// ---------------------------------------------------------------------------
// 4) out = dropout(relu((agg @ W) * rsqrt(max(deg_in,1)) + b))
//    MFMA bf16 16x16x32.  Block = 64 rows x 256 cols, 4 waves (wave: 64x64).
//    A staged once in LDS (37 KB -> 4 blocks/CU); B direct from L2 Wt.
// ---------------------------------------------------------------------------
#define APAD 280  // shorts per As row (560 B, 16B-aligned)
__global__ __launch_bounds__(256, 4) void gemm_mfma_kernel(
    const uint16_t* __restrict__ agg, const uint16_t* __restrict__ Wt,
    const float* __restrict__ bias, const int* __restrict__ deg_in,
    const uint32_t* __restrict__ mask, float* __restrict__ out) {
  __shared__ short As[64 * APAD];
  __shared__ float sdeg[64];
  __shared__ float sbias[256];

  const int tid = threadIdx.x;
  const int r0 = blockIdx.x * 64;
  const int lane = tid & 63;
  const int seg = lane >> 4;  // k-segment 0..3
  const int l15 = lane & 15;
  const int wc = tid >> 6;  // wave -> col panel (64 cols each)

  sbias[tid] = bias[tid];
  if (tid < 64) {
    const int r = r0 + tid;
    sdeg[tid] = (r < N_NODES) ? rsqrtf(fmaxf((float)deg_in[r], 1.0f)) : 0.0f;
  }

  // stage A panel: 64 rows x 256 k bf16 (2048 x 16B chunks, coalesced)
  {
    const uint16_t* ap = agg + (size_t)r0 * DDIM;
#pragma unroll
    for (int it = 0; it < 8; ++it) {
      const int c = tid + 256 * it;
      const int row = c >> 5;        // 32 chunks per row
      const int k8 = (c & 31) << 3;  // 0,8,...,248
      int4 v = make_int4(0, 0, 0, 0);
      if (r0 + row < N_NODES) v = *(const int4*)(ap + (size_t)row * DDIM + k8);
      *(int4*)&As[row * APAD + k8] = v;
    }
  }
  __syncthreads();

  const uint16_t* wt_base = Wt + (size_t)(wc * 64 + l15) * DDIM + seg * 8;

  f32x4 acc[4][4] = {};
#pragma unroll
  for (int kkI = 0; kkI < 8; ++kkI) {
    const int kk = kkI * 32;
    bf16x8 a[4], b[4];
#pragma unroll
    for (int m = 0; m < 4; ++m)
      a[m] = *(const bf16x8*)&As[(m * 16 + l15) * APAD + kk + seg * 8];
#pragma unroll
    for (int n = 0; n < 4; ++n)
      b[n] = *(const bf16x8*)(wt_base + n * 16 * DDIM + kk);
#pragma unroll
    for (int m = 0; m < 4; ++m)
#pragma unroll
      for (int n = 0; n < 4; ++n)
        acc[m][n] = __builtin_amdgcn_mfma_f32_16x16x32_bf16(a[m], b[n], acc[m][n], 0, 0, 0);
  }

  // epilogue: C/D layout col = lane&15, row = seg*4 + reg
  constexpr float INV09 = 1.0f / 0.9f;
#pragma unroll
  for (int m = 0; m < 4; ++m) {
#pragma unroll
    for (int r = 0; r < 4; ++r) {
      const int lrow = m * 16 + seg * 4 + r;
      const int row = r0 + lrow;
      if (row >= N_NODES) continue;
      const float s = sdeg[lrow];
      const uint32_t w0 = mask[row * 8 + wc * 2];      // cols wc*64 .. +31
      const uint32_t w1 = mask[row * 8 + wc * 2 + 1];  // cols wc*64+32 .. +63
#pragma unroll
      for (int n = 0; n < 4; ++n) {
        const int col = wc * 64 + n * 16 + l15;
        float v = fmaxf(acc[m][n][r] * s + sbias[col], 0.0f);
        const uint32_t w = (n < 2) ? w0 : w1;
        const uint32_t bit = (uint32_t)((n & 1) * 16 + l15);
        out[(size_t)row * DDIM + col] = ((w >> bit) & 1u) ? v * INV09 : 0.0f;
      }
    }
  }
}

// ---------------------------------------------------------------------------
// ws layout (bytes; ws_size ~268 MB per harness poison fill):
//   deg_out   @ 0          (200000)
//   deg_in    @ 200000     (200000)
//   esrc      @ 400000     (12800000)  padded CSR [n][64]
//   Wt bf16   @ 13200000   (131072)
//   featb bf16@ 13331072   (25600000)
//   mask u32  @ 38931072   (1600000)
//   agg bf16  @ 40531072   (25600000)  total ~66 MB
// ---------------------------------------------------------------------------
extern "C" void kernel_launch(void* const* d_in, const int* in_sizes, int n_in,
                              void* d_out, int out_size, void* d_ws, size_t ws_size,
                              hipStream_t stream) {
  const float* feat = (const float*)d_in[0];
  const float* W = (const float*)d_in[1];
  const float* bias = (const float*)d_in[2];
  const int* src = (const int*)d_in[3];
  const int* dst = (const int*)d_in[4];
  float* out = (float*)d_out;

  char* ws = (char*)d_ws;
  int* deg_out = (int*)(ws + 0);
  int* deg_in = (int*)(ws + 200000);
  int* esrc = (int*)(ws + 400000);
  uint16_t* Wt = (uint16_t*)(ws + 13200000);
  uint16_t* featb = (uint16_t*)(ws + 13331072);
  uint32_t* mask = (uint32_t*)(ws + 38931072);
  uint16_t* agg = (uint16_t*)(ws + 40531072);

  setup_kernel<<<162, 256, 0, stream>>>(W, Wt, (int4*)d_ws);
  mega_prep_kernel<<<EDGE_BLOCKS + MASK_BLOCKS + FCONV_BLOCKS, 256, 0, stream>>>(
      feat, src, dst, deg_out, deg_in, esrc, mask, featb);
  gather_kernel<<<(N_NODES + 3) / 4, 256, 0, stream>>>(featb, deg_out, deg_in, esrc, agg);
  gemm_mfma_kernel<<<(N_NODES + 63) / 64, 256, 0, stream>>>(agg, Wt, bias, deg_in, mask, out);
}

// Round 23
// 111.012 us; speedup vs baseline: 1.2189x; 1.0104x over previous
//
#include <hip/hip_runtime.h>
#include <stdint.h>

#define N_NODES 50000
#define N_EDGES 400000
#define DDIM 256
#define MASK_WORDS 400000  // 50000*256/32
#define EDGE_CAP 64        // padded CSR row capacity (max in-degree ~30)
#define EDGE_BLOCKS 98     // ceil(400000/16/256), 16 edges per thread
#define MASK_BLOCKS 1563   // ceil(400000/256)
#define FCONV_BLOCKS 6250  // 50000*256/8 / 256

typedef __attribute__((ext_vector_type(8))) short bf16x8;
typedef __attribute__((ext_vector_type(4))) float f32x4;

// ---------------------------------------------------------------------------
// JAX threefry2x32, key = (0, 42).  Partitionable scheme (verified round 5):
// element with flat index j uses counter (0, j); draw = out0 ^ out1.
// ---------------------------------------------------------------------------
__device__ __forceinline__ uint32_t rotl32(uint32_t x, uint32_t r) {
  return (x << r) | (x >> (32u - r));
}

__device__ __forceinline__ uint32_t threefry_draw_0_42(uint32_t x0, uint32_t x1) {
  const uint32_t k0 = 0u, k1 = 42u;
  const uint32_t k2 = k0 ^ k1 ^ 0x1BD11BDAu;
  x0 += k0;
  x1 += k1;
#define TF_ROUND(r)          \
  {                          \
    x0 += x1;                \
    x1 = rotl32(x1, r);      \
    x1 ^= x0;                \
  }
  TF_ROUND(13) TF_ROUND(15) TF_ROUND(26) TF_ROUND(6)
  x0 += k1; x1 += k2 + 1u;
  TF_ROUND(17) TF_ROUND(29) TF_ROUND(16) TF_ROUND(24)
  x0 += k2; x1 += k0 + 2u;
  TF_ROUND(13) TF_ROUND(15) TF_ROUND(26) TF_ROUND(6)
  x0 += k0; x1 += k1 + 3u;
  TF_ROUND(17) TF_ROUND(29) TF_ROUND(16) TF_ROUND(24)
  x0 += k1; x1 += k2 + 4u;
  TF_ROUND(13) TF_ROUND(15) TF_ROUND(26) TF_ROUND(6)
  x0 += k2; x1 += k0 + 5u;
#undef TF_ROUND
  return x0 ^ x1;
}

__device__ __forceinline__ uint16_t bf16_rne(float x) {
  uint32_t u = __float_as_uint(x);
  u += 0x7FFFu + ((u >> 16) & 1u);
  return (uint16_t)(u >> 16);
}

// ---------------------------------------------------------------------------
// 1) setup: blocks 0-97 zero deg_out+deg_in (25000 int4);
//           blocks 98-161 transpose W fp32 [k][n] -> Wt bf16 [n][k]
// ---------------------------------------------------------------------------
__global__ __launch_bounds__(256) void setup_kernel(
    const float* __restrict__ W, uint16_t* __restrict__ Wt,
    int4* __restrict__ zero_base) {
  const int bid = blockIdx.x;
  if (bid < 98) {
    const int t = bid * 256 + threadIdx.x;
    if (t < 25000) zero_base[t] = make_int4(0, 0, 0, 0);
  } else {
    const int t = (bid - 98) * 256 + threadIdx.x;  // 0..16383
    const int n = t >> 6;
    const int k4 = (t & 63) << 2;
    ushort4 p;
    p.x = bf16_rne(W[(size_t)(k4 + 0) * DDIM + n]);
    p.y = bf16_rne(W[(size_t)(k4 + 1) * DDIM + n]);
    p.z = bf16_rne(W[(size_t)(k4 + 2) * DDIM + n]);
    p.w = bf16_rne(W[(size_t)(k4 + 3) * DDIM + n]);
    *(ushort4*)(Wt + (size_t)n * DDIM + k4) = p;
  }
}

// ---------------------------------------------------------------------------
// 2) MEGA-FUSED prep (r22 structure; esrc now uint16 — src<50000<65536 —
//    halving the random-scatter write-allocate traffic that r21/r22 counters
//    exposed as the edge pass's real cost):
//      [0, 98)               edge pass, 16 edges/thread
//      [98, 1661)            dropout bitmask (pure VALU, hides under edges)
//      [1661, 7911)          featb = bf16(feat)  (pure convert, BW-bound)
// ---------------------------------------------------------------------------
__global__ __launch_bounds__(256) void mega_prep_kernel(
    const float* __restrict__ feat, const int* __restrict__ src,
    const int* __restrict__ dst, int* __restrict__ deg_out,
    int* __restrict__ deg_in, uint16_t* __restrict__ esrc,
    uint32_t* __restrict__ mask, uint16_t* __restrict__ featb) {
  const int bid = blockIdx.x;
  if (bid < EDGE_BLOCKS) {
    const int base = (bid * 256 + threadIdx.x) * 16;
    if (base < N_EDGES) {  // N_EDGES%16==0 -> full int4 quads in bounds
#pragma unroll
      for (int h = 0; h < 2; ++h) {
        const int b8 = base + h * 8;
        const int4 sa = *(const int4*)(src + b8);
        const int4 sb = *(const int4*)(src + b8 + 4);
        const int4 da = *(const int4*)(dst + b8);
        const int4 db = *(const int4*)(dst + b8 + 4);
        atomicAdd(&deg_out[sa.x], 1);
        atomicAdd(&deg_out[sa.y], 1);
        atomicAdd(&deg_out[sa.z], 1);
        atomicAdd(&deg_out[sa.w], 1);
        atomicAdd(&deg_out[sb.x], 1);
        atomicAdd(&deg_out[sb.y], 1);
        atomicAdd(&deg_out[sb.z], 1);
        atomicAdd(&deg_out[sb.w], 1);
        const int p0 = atomicAdd(&deg_in[da.x], 1);
        const int p1 = atomicAdd(&deg_in[da.y], 1);
        const int p2 = atomicAdd(&deg_in[da.z], 1);
        const int p3 = atomicAdd(&deg_in[da.w], 1);
        const int p4 = atomicAdd(&deg_in[db.x], 1);
        const int p5 = atomicAdd(&deg_in[db.y], 1);
        const int p6 = atomicAdd(&deg_in[db.z], 1);
        const int p7 = atomicAdd(&deg_in[db.w], 1);
        if (p0 < EDGE_CAP) esrc[(da.x << 6) + p0] = (uint16_t)sa.x;
        if (p1 < EDGE_CAP) esrc[(da.y << 6) + p1] = (uint16_t)sa.y;
        if (p2 < EDGE_CAP) esrc[(da.z << 6) + p2] = (uint16_t)sa.z;
        if (p3 < EDGE_CAP) esrc[(da.w << 6) + p3] = (uint16_t)sa.w;
        if (p4 < EDGE_CAP) esrc[(db.x << 6) + p4] = (uint16_t)sb.x;
        if (p5 < EDGE_CAP) esrc[(db.y << 6) + p5] = (uint16_t)sb.y;
        if (p6 < EDGE_CAP) esrc[(db.z << 6) + p6] = (uint16_t)sb.z;
        if (p7 < EDGE_CAP) esrc[(db.w << 6) + p7] = (uint16_t)sb.w;
      }
    }
  } else if (bid < EDGE_BLOCKS + MASK_BLOCKS) {
    // dropout bitmask; keep(j) <=> (draw>>9) < 7549747 (== u<0.9f exactly)
    const uint32_t t =
        (uint32_t)(bid - EDGE_BLOCKS) * 256u + (uint32_t)threadIdx.x;
    if (t < MASK_WORDS) {
      const uint32_t base = t * 32u;
      uint32_t w = 0u;
#pragma unroll
      for (uint32_t b = 0; b < 32u; ++b) {
        const uint32_t bits = threefry_draw_0_42(0u, base + b);
        w |= ((bits >> 9) < 7549747u) ? (1u << b) : 0u;
      }
      mask[t] = w;
    }
  } else {
    // featb = bf16(feat)  (unscaled; gather applies rsqrt(deg_out) per edge)
    const int t = (bid - EDGE_BLOCKS - MASK_BLOCKS) * 256 + threadIdx.x;
    const size_t base = (size_t)t * 8;
    const float4 a = *(const float4*)(feat + base);
    const float4 b = *(const float4*)(feat + base + 4);
    ushort4 lo, hi;
    lo.x = bf16_rne(a.x); lo.y = bf16_rne(a.y);
    lo.z = bf16_rne(a.z); lo.w = bf16_rne(a.w);
    hi.x = bf16_rne(b.x); hi.y = bf16_rne(b.y);
    hi.z = bf16_rne(b.z); hi.w = bf16_rne(b.w);
    *(ushort4*)(featb + base) = lo;
    *(ushort4*)(featb + base + 4) = hi;
  }
}

// ---------------------------------------------------------------------------
// 3) pull-mode aggregate: FULL wave per node; lane owns 4 bf16 (uint2) of
//    the 256-col row.  esrc is u16: ONE uint4 load = 8 edge indices.
//    8 edge rows + deg scales back-to-back, fp32 fma; 4/2/1 ladder tail.
//    scale = rsqrt(max(deg_out[src],1)).
// ---------------------------------------------------------------------------
__device__ __forceinline__ void acc4s(float* a, uint2 q, float sc) {
  a[0] = fmaf(__uint_as_float(q.x << 16), sc, a[0]);
  a[1] = fmaf(__uint_as_float(q.x & 0xFFFF0000u), sc, a[1]);
  a[2] = fmaf(__uint_as_float(q.y << 16), sc, a[2]);
  a[3] = fmaf(__uint_as_float(q.y & 0xFFFF0000u), sc, a[3]);
}

__device__ __forceinline__ float dscale(const int* deg, int s) {
  return rsqrtf(fmaxf((float)deg[s], 1.0f));
}

__global__ __launch_bounds__(256) void gather_kernel(
    const uint16_t* __restrict__ featb, const int* __restrict__ deg_out,
    const int* __restrict__ deg_in, const uint16_t* __restrict__ esrc,
    uint16_t* __restrict__ agg) {
  const int n = blockIdx.x * 4 + (threadIdx.x >> 6);
  if (n >= N_NODES) return;
  const int lane = threadIdx.x & 63;
  const size_t coff = (size_t)(lane << 2);  // 4 bf16 = 8 B per lane
  const uint16_t* es = esrc + ((size_t)n << 6);
  const int cnt = min(deg_in[n], EDGE_CAP);

  float a[4] = {};
  int j = 0;
  for (; j + 8 <= cnt; j += 8) {
    const uint4 ee = *(const uint4*)(es + j);  // 8 u16 edge indices
    const int s0 = (int)(ee.x & 0xFFFFu);
    const int s1 = (int)(ee.x >> 16);
    const int s2 = (int)(ee.y & 0xFFFFu);
    const int s3 = (int)(ee.y >> 16);
    const int s4 = (int)(ee.z & 0xFFFFu);
    const int s5 = (int)(ee.z >> 16);
    const int s6 = (int)(ee.w & 0xFFFFu);
    const int s7 = (int)(ee.w >> 16);
    const uint2 q0 = *(const uint2*)(featb + (size_t)s0 * DDIM + coff);
    const uint2 q1 = *(const uint2*)(featb + (size_t)s1 * DDIM + coff);
    const uint2 q2 = *(const uint2*)(featb + (size_t)s2 * DDIM + coff);
    const uint2 q3 = *(const uint2*)(featb + (size_t)s3 * DDIM + coff);
    const uint2 q4 = *(const uint2*)(featb + (size_t)s4 * DDIM + coff);
    const uint2 q5 = *(const uint2*)(featb + (size_t)s5 * DDIM + coff);
    const uint2 q6 = *(const uint2*)(featb + (size_t)s6 * DDIM + coff);
    const uint2 q7 = *(const uint2*)(featb + (size_t)s7 * DDIM + coff);
    const float f0 = dscale(deg_out, s0);
    const float f1 = dscale(deg_out, s1);
    const float f2 = dscale(deg_out, s2);
    const float f3 = dscale(deg_out, s3);
    const float f4 = dscale(deg_out, s4);
    const float f5 = dscale(deg_out, s5);
    const float f6 = dscale(deg_out, s6);
    const float f7 = dscale(deg_out, s7);
    acc4s(a, q0, f0); acc4s(a, q1, f1); acc4s(a, q2, f2); acc4s(a, q3, f3);
    acc4s(a, q4, f4); acc4s(a, q5, f5); acc4s(a, q6, f6); acc4s(a, q7, f7);
  }
  if (j + 4 <= cnt) {
    const uint2 ee = *(const uint2*)(es + j);
    const int s0 = (int)(ee.x & 0xFFFFu);
    const int s1 = (int)(ee.x >> 16);
    const int s2 = (int)(ee.y & 0xFFFFu);
    const int s3 = (int)(ee.y >> 16);
    const uint2 q0 = *(const uint2*)(featb + (size_t)s0 * DDIM + coff);
    const uint2 q1 = *(const uint2*)(featb + (size_t)s1 * DDIM + coff);
    const uint2 q2 = *(const uint2*)(featb + (size_t)s2 * DDIM + coff);
    const uint2 q3 = *(const uint2*)(featb + (size_t)s3 * DDIM + coff);
    const float f0 = dscale(deg_out, s0);
    const float f1 = dscale(deg_out, s1);
    const float f2 = dscale(deg_out, s2);
    const float f3 = dscale(deg_out, s3);
    acc4s(a, q0, f0); acc4s(a, q1, f1); acc4s(a, q2, f2); acc4s(a, q3, f3);
    j += 4;
  }
  if (j + 2 <= cnt) {
    const uint32_t ee = *(const uint32_t*)(es + j);
    const int s0 = (int)(ee & 0xFFFFu);
    const int s1 = (int)(ee >> 16);
    const uint2 q0 = *(const uint2*)(featb + (size_t)s0 * DDIM + coff);
    const uint2 q1 = *(const uint2*)(featb + (size_t)s1 * DDIM + coff);
    acc4s(a, q0, dscale(deg_out, s0));
    acc4s(a, q1, dscale(deg_out, s1));
    j += 2;
  }
  if (j < cnt) {
    const int s0 = (int)es[j];
    const uint2 q0 = *(const uint2*)(featb + (size_t)s0 * DDIM + coff);
    acc4s(a, q0, dscale(deg_out, s0));
  }

  uint2 p;
  p.x = (uint32_t)bf16_rne(a[0]) | ((uint32_t)bf16_rne(a[1]) << 16);
  p.y = (uint32_t)bf16_rne(a[2]) | ((uint32_t)bf16_rne(a[3]) << 16);
  *(uint2*)(agg + (size_t)n * DDIM + coff) = p;
}

// ---------------------------------------------------------------------------
// 4) out = dropout(relu((agg @ W) * rsqrt(max(deg_in,1)) + b))
//    MFMA bf16 16x16x32.  Block = 64 rows x 256 cols, 4 waves (wave: 64x64).
//    A staged once in LDS (37 KB -> 4 blocks/CU); B direct from L2 Wt.
// ---------------------------------------------------------------------------
#define APAD 280  // shorts per As row (560 B, 16B-aligned)
__global__ __launch_bounds__(256, 4) void gemm_mfma_kernel(
    const uint16_t* __restrict__ agg, const uint16_t* __restrict__ Wt,
    const float* __restrict__ bias, const int* __restrict__ deg_in,
    const uint32_t* __restrict__ mask, float* __restrict__ out) {
  __shared__ short As[64 * APAD];
  __shared__ float sdeg[64];
  __shared__ float sbias[256];

  const int tid = threadIdx.x;
  const int r0 = blockIdx.x * 64;
  const int lane = tid & 63;
  const int seg = lane >> 4;  // k-segment 0..3
  const int l15 = lane & 15;
  const int wc = tid >> 6;  // wave -> col panel (64 cols each)

  sbias[tid] = bias[tid];
  if (tid < 64) {
    const int r = r0 + tid;
    sdeg[tid] = (r < N_NODES) ? rsqrtf(fmaxf((float)deg_in[r], 1.0f)) : 0.0f;
  }

  // stage A panel: 64 rows x 256 k bf16 (2048 x 16B chunks, coalesced)
  {
    const uint16_t* ap = agg + (size_t)r0 * DDIM;
#pragma unroll
    for (int it = 0; it < 8; ++it) {
      const int c = tid + 256 * it;
      const int row = c >> 5;        // 32 chunks per row
      const int k8 = (c & 31) << 3;  // 0,8,...,248
      int4 v = make_int4(0, 0, 0, 0);
      if (r0 + row < N_NODES) v = *(const int4*)(ap + (size_t)row * DDIM + k8);
      *(int4*)&As[row * APAD + k8] = v;
    }
  }
  __syncthreads();

  const uint16_t* wt_base = Wt + (size_t)(wc * 64 + l15) * DDIM + seg * 8;

  f32x4 acc[4][4] = {};
#pragma unroll
  for (int kkI = 0; kkI < 8; ++kkI) {
    const int kk = kkI * 32;
    bf16x8 a[4], b[4];
#pragma unroll
    for (int m = 0; m < 4; ++m)
      a[m] = *(const bf16x8*)&As[(m * 16 + l15) * APAD + kk + seg * 8];
#pragma unroll
    for (int n = 0; n < 4; ++n)
      b[n] = *(const bf16x8*)(wt_base + n * 16 * DDIM + kk);
#pragma unroll
    for (int m = 0; m < 4; ++m)
#pragma unroll
      for (int n = 0; n < 4; ++n)
        acc[m][n] = __builtin_amdgcn_mfma_f32_16x16x32_bf16(a[m], b[n], acc[m][n], 0, 0, 0);
  }

  // epilogue: C/D layout col = lane&15, row = seg*4 + reg
  constexpr float INV09 = 1.0f / 0.9f;
#pragma unroll
  for (int m = 0; m < 4; ++m) {
#pragma unroll
    for (int r = 0; r < 4; ++r) {
      const int lrow = m * 16 + seg * 4 + r;
      const int row = r0 + lrow;
      if (row >= N_NODES) continue;
      const float s = sdeg[lrow];
      const uint32_t w0 = mask[row * 8 + wc * 2];      // cols wc*64 .. +31
      const uint32_t w1 = mask[row * 8 + wc * 2 + 1];  // cols wc*64+32 .. +63
#pragma unroll
      for (int n = 0; n < 4; ++n) {
        const int col = wc * 64 + n * 16 + l15;
        float v = fmaxf(acc[m][n][r] * s + sbias[col], 0.0f);
        const uint32_t w = (n < 2) ? w0 : w1;
        const uint32_t bit = (uint32_t)((n & 1) * 16 + l15);
        out[(size_t)row * DDIM + col] = ((w >> bit) & 1u) ? v * INV09 : 0.0f;
      }
    }
  }
}

// ---------------------------------------------------------------------------
// ws layout (bytes; ws_size ~268 MB per harness poison fill):
//   deg_out    @ 0          (200000)
//   deg_in     @ 200000     (200000)
//   esrc u16   @ 400000     (6400000)   padded CSR [n][64], uint16
//   Wt bf16    @ 6800000    (131072)
//   featb bf16 @ 6931072    (25600000)
//   mask u32   @ 32531072   (1600000)
//   agg bf16   @ 34131072   (25600000)  total ~60 MB
// ---------------------------------------------------------------------------
extern "C" void kernel_launch(void* const* d_in, const int* in_sizes, int n_in,
                              void* d_out, int out_size, void* d_ws, size_t ws_size,
                              hipStream_t stream) {
  const float* feat = (const float*)d_in[0];
  const float* W = (const float*)d_in[1];
  const float* bias = (const float*)d_in[2];
  const int* src = (const int*)d_in[3];
  const int* dst = (const int*)d_in[4];
  float* out = (float*)d_out;

  char* ws = (char*)d_ws;
  int* deg_out = (int*)(ws + 0);
  int* deg_in = (int*)(ws + 200000);
  uint16_t* esrc = (uint16_t*)(ws + 400000);
  uint16_t* Wt = (uint16_t*)(ws + 6800000);
  uint16_t* featb = (uint16_t*)(ws + 6931072);
  uint32_t* mask = (uint32_t*)(ws + 32531072);
  uint16_t* agg = (uint16_t*)(ws + 34131072);

  setup_kernel<<<162, 256, 0, stream>>>(W, Wt, (int4*)d_ws);
  mega_prep_kernel<<<EDGE_BLOCKS + MASK_BLOCKS + FCONV_BLOCKS, 256, 0, stream>>>(
      feat, src, dst, deg_out, deg_in, esrc, mask, featb);
  gather_kernel<<<(N_NODES + 3) / 4, 256, 0, stream>>>(featb, deg_out, deg_in, esrc, agg);
  gemm_mfma_kernel<<<(N_NODES + 63) / 64, 256, 0, stream>>>(agg, Wt, bias, deg_in, mask, out);
}